// Round 4
// baseline (262.047 us; speedup 1.0000x reference)
//
#include <hip/hip_runtime.h>

#define F_IN 128
#define DIM_H 256
#define N_CLASSES 40
#define BN_EPS 1e-5f
#define M_PAD 50176

typedef short bf16x8 __attribute__((ext_vector_type(8)));
typedef float f32x4 __attribute__((ext_vector_type(4)));

__device__ __forceinline__ unsigned short f2bf(float f) {
    union { float f; unsigned u; } v; v.f = f;
    unsigned r = v.u + 0x7fff + ((v.u >> 16) & 1);  // RNE
    return (unsigned short)(r >> 16);
}
__device__ __forceinline__ float bf2f(unsigned short u) {
    union { unsigned u; float f; } v; v.u = ((unsigned)u) << 16;
    return v.f;
}
__device__ __forceinline__ float4 bf2f4(ushort4 u) {
    return make_float4(bf2f(u.x), bf2f(u.y), bf2f(u.z), bf2f(u.w));
}

// ---------------- Phase A: histogram of dst ----------------
__global__ void hist_kernel(const int* __restrict__ dst, int* __restrict__ hist, int nE) {
    int e = blockIdx.x * blockDim.x + threadIdx.x;
    if (e >= nE) return;
    atomicAdd(&hist[dst[e]], 1);
}

// ---------------- Phase B: single-kernel scan (fused blocks+final) ----------------
// Each block computes its global prefix by directly summing hist[0..base).
// Also seeds cursor[i] = start[i] so fill_kernel needs no start[] read.
__global__ void scan_kernel(const int* __restrict__ hist,
                            int* __restrict__ start, int* __restrict__ cursor,
                            int M, int nE) {
    __shared__ int lds[256];
    __shared__ int s_prefix;
    int t = threadIdx.x;
    int base = blockIdx.x * 256;
    int s = 0;
    for (int i = t; i < base; i += 256) s += hist[i];
    lds[t] = s;
    __syncthreads();
    for (int o = 128; o > 0; o >>= 1) {
        if (t < o) lds[t] += lds[t + o];
        __syncthreads();
    }
    if (t == 0) s_prefix = lds[0];
    __syncthreads();
    int prefix = s_prefix;
    __syncthreads();           // lds reuse below
    int i = base + t;
    int orig = (i < M) ? hist[i] : 0;
    lds[t] = orig;
    __syncthreads();
    for (int o = 1; o < 256; o <<= 1) {
        int v = (t >= o) ? lds[t - o] : 0;
        __syncthreads();
        lds[t] += v;
        __syncthreads();
    }
    if (i < M) {
        int v = prefix + lds[t] - orig;
        start[i] = v;
        cursor[i] = v;
    }
    if (blockIdx.x == 0 && t == 0) start[M] = nE;
}

// ---------------- Phase C: bucket-fill src indices ----------------
__global__ void fill_kernel(const int* __restrict__ src, const int* __restrict__ dst,
                            int* __restrict__ cursor,
                            int* __restrict__ order, int nE) {
    int e = blockIdx.x * blockDim.x + threadIdx.x;
    if (e >= nE) return;
    int pos = atomicAdd(&cursor[dst[e]], 1);
    order[pos] = src[e];
}

// ---------------- prep: xb = bf16(x), weight transposes, hist zeroing ----------------
__global__ void prep_kernel(const float* __restrict__ x, unsigned short* __restrict__ xb,
                            const float* __restrict__ W1, const float* __restrict__ W2,
                            const float* __restrict__ Wl,
                            unsigned short* __restrict__ W1t,
                            unsigned short* __restrict__ W2t,
                            unsigned short* __restrict__ Wlt,
                            int* __restrict__ histz, int XQ, int ZQ) {
    int idx = blockIdx.x * 256 + threadIdx.x;
    if (idx < XQ) {
        float4 v = ((const float4*)x)[idx];
        ushort4 o;
        o.x = f2bf(v.x); o.y = f2bf(v.y); o.z = f2bf(v.z); o.w = f2bf(v.w);
        ((ushort4*)xb)[idx] = o;
        return;
    }
    int j = idx - XQ;
    if (j < 32768) {                    // W1t: [n=256][k=128]
        int n = j >> 7, k = j & 127;
        W1t[j] = f2bf(W1[k * DIM_H + n]);
    } else if (j < 32768 + 65536) {     // W2t: [n=256][k=256]
        int i = j - 32768;
        int n = i >> 8, k = i & 255;
        W2t[i] = f2bf(W2[k * DIM_H + n]);
    } else if (j < 32768 + 65536 + 16384) {  // Wlt: [n=64][k=256]
        int i = j - 98304;
        int n = i >> 8, k = i & 255;
        Wlt[i] = f2bf((n < N_CLASSES) ? Wl[k * N_CLASSES + n] : 0.f);
    } else {
        int z = j - 114688;
        if (z >= 0 && z < ZQ) ((int4*)histz)[z] = make_int4(0, 0, 0, 0);
    }
}

// ---------------- BN reduce ----------------
__global__ void bn_reduce_kernel(const float* __restrict__ partials, int R,
                                 const float* __restrict__ gamma,
                                 const float* __restrict__ beta,
                                 float* __restrict__ scale,
                                 float* __restrict__ shift, int M) {
    __shared__ float ls[256], lss[256];
    int c = blockIdx.x, t = threadIdx.x;
    float s = 0.f, ss = 0.f;
    for (int r = t; r < R; r += 256) {
        s += partials[(long)r * 512 + c];
        ss += partials[(long)r * 512 + 256 + c];
    }
    ls[t] = s; lss[t] = ss;
    __syncthreads();
    for (int o = 128; o > 0; o >>= 1) {
        if (t < o) { ls[t] += ls[t + o]; lss[t] += lss[t + o]; }
        __syncthreads();
    }
    if (t == 0) {
        float inv = 1.0f / (float)M;
        float mean = ls[0] * inv;
        float var = lss[0] * inv - mean * mean;
        float sc = gamma[c] * rsqrtf(var + BN_EPS);
        scale[c] = sc;
        shift[c] = beta[c] - mean * sc;
    }
}

// ---------------- fused gather + GEMM1 ----------------
// Each block gathers its 128-row A-tile (x + sum of neighbor rows, bf16)
// straight into LDS, then runs the 128x256 MFMA GEMM from it.
// A tile: [128][128] shorts, XOR-swizzled 16B granules (injective: row bits
// 3-5 XOR'd into a 128-short row; verified write/read-consistent).
// B (W1t): PADDED rows (PB=40), double-buffered — the round-2 proven layout.
// LDS = 16384 (A) + 2*10240 (B) = 36864 shorts = 72 KiB; 2 blocks/CU.
// Epilogue h1t [128][PH=264] (padded, proven) aliases the whole region.
__global__ __launch_bounds__(512, 4) void gg1_kernel(
    const unsigned short* __restrict__ xb,
    const int* __restrict__ order, const int* __restrict__ start,
    const unsigned short* __restrict__ W1t,
    const float* __restrict__ b1, unsigned short* __restrict__ h1,
    float* __restrict__ partials, int M) {
    constexpr int S = 4;
    constexpr int PB = 40, PH = 264;
    __shared__ __align__(16) unsigned short lds[36864];   // 72 KiB
    unsigned short* As = lds;                 // [128][128] swizzled
    unsigned short* h1t = lds;                // epilogue alias [128][PH]

    int tid = threadIdx.x;
    int wave = tid >> 6, lane = tid & 63;
    int wm = wave >> 2, wn = wave & 3;
    int l15 = lane & 15, q = lane >> 4;
    long row0 = (long)blockIdx.x * 128;

    // ---- Phase 1: gather A-tile. 16 half-waves x 8 consecutive rows each ----
    {
        const ushort4* xv = (const ushort4*)xb;
        int g = tid >> 5, lane32 = tid & 31;
        for (int it = 0; it < 8; ++it) {
            int r = g * 8 + it;
            long node = row0 + r;
            unsigned short* arow = As + r * 128 + ((lane32 * 4) ^ ((r & 7) << 3));
            if (node < M) {
                float4 a0 = bf2f4(xv[(size_t)node * 32 + lane32]);  // self term
                float4 a1 = make_float4(0.f, 0.f, 0.f, 0.f);
                float4 a2 = a1, a3 = a1;
                int e0 = start[node], e1 = start[node + 1];
                int e = e0;
                for (; e + 8 <= e1; e += 8) {
                    int s0 = order[e],     s1 = order[e + 1], s2 = order[e + 2], s3 = order[e + 3];
                    int s4 = order[e + 4], s5 = order[e + 5], s6 = order[e + 6], s7 = order[e + 7];
                    ushort4 u0 = xv[(size_t)s0 * 32 + lane32];
                    ushort4 u1 = xv[(size_t)s1 * 32 + lane32];
                    ushort4 u2 = xv[(size_t)s2 * 32 + lane32];
                    ushort4 u3 = xv[(size_t)s3 * 32 + lane32];
                    ushort4 u4 = xv[(size_t)s4 * 32 + lane32];
                    ushort4 u5 = xv[(size_t)s5 * 32 + lane32];
                    ushort4 u6 = xv[(size_t)s6 * 32 + lane32];
                    ushort4 u7 = xv[(size_t)s7 * 32 + lane32];
                    float4 v0 = bf2f4(u0), v1 = bf2f4(u1), v2 = bf2f4(u2), v3 = bf2f4(u3);
                    float4 v4 = bf2f4(u4), v5 = bf2f4(u5), v6 = bf2f4(u6), v7 = bf2f4(u7);
                    a0.x += v0.x; a0.y += v0.y; a0.z += v0.z; a0.w += v0.w;
                    a1.x += v1.x; a1.y += v1.y; a1.z += v1.z; a1.w += v1.w;
                    a2.x += v2.x; a2.y += v2.y; a2.z += v2.z; a2.w += v2.w;
                    a3.x += v3.x; a3.y += v3.y; a3.z += v3.z; a3.w += v3.w;
                    a0.x += v4.x; a0.y += v4.y; a0.z += v4.z; a0.w += v4.w;
                    a1.x += v5.x; a1.y += v5.y; a1.z += v5.z; a1.w += v5.w;
                    a2.x += v6.x; a2.y += v6.y; a2.z += v6.z; a2.w += v6.w;
                    a3.x += v7.x; a3.y += v7.y; a3.z += v7.z; a3.w += v7.w;
                }
                for (; e + 4 <= e1; e += 4) {
                    int s0 = order[e], s1 = order[e + 1], s2 = order[e + 2], s3 = order[e + 3];
                    float4 v0 = bf2f4(xv[(size_t)s0 * 32 + lane32]);
                    float4 v1 = bf2f4(xv[(size_t)s1 * 32 + lane32]);
                    float4 v2 = bf2f4(xv[(size_t)s2 * 32 + lane32]);
                    float4 v3 = bf2f4(xv[(size_t)s3 * 32 + lane32]);
                    a0.x += v0.x; a0.y += v0.y; a0.z += v0.z; a0.w += v0.w;
                    a1.x += v1.x; a1.y += v1.y; a1.z += v1.z; a1.w += v1.w;
                    a2.x += v2.x; a2.y += v2.y; a2.z += v2.z; a2.w += v2.w;
                    a3.x += v3.x; a3.y += v3.y; a3.z += v3.z; a3.w += v3.w;
                }
                for (; e < e1; ++e) {
                    float4 v = bf2f4(xv[(size_t)order[e] * 32 + lane32]);
                    a1.x += v.x; a1.y += v.y; a1.z += v.z; a1.w += v.w;
                }
                float4 t;
                t.x = (a0.x + a1.x) + (a2.x + a3.x);
                t.y = (a0.y + a1.y) + (a2.y + a3.y);
                t.z = (a0.z + a1.z) + (a2.z + a3.z);
                t.w = (a0.w + a1.w) + (a2.w + a3.w);
                ushort4 o;
                o.x = f2bf(t.x); o.y = f2bf(t.y); o.z = f2bf(t.z); o.w = f2bf(t.w);
                *(ushort4*)arow = o;
            } else {
                *(ushort4*)arow = make_ushort4(0, 0, 0, 0);  // pad rows: clean zeros
            }
        }
    }

    // ---- Phase 2: GEMM from LDS A-tile; B staged per step (padded), dbuf ----
    bf16x8 br[2];
    auto loadB = [&](int s) {
#pragma unroll
        for (int i = 0; i < 2; ++i) {
            int ch = tid + i * 512;          // 1024 chunks of 8 shorts
            int m = ch >> 2, c = ch & 3;
            br[i] = *(const bf16x8*)(W1t + m * F_IN + s * 32 + c * 8);
        }
    };
    auto writeB = [&](int buf) {
        unsigned short* Bs = lds + 16384 + buf * 10240;
#pragma unroll
        for (int i = 0; i < 2; ++i) {
            int ch = tid + i * 512;
            int m = ch >> 2, c = ch & 3;
            *(bf16x8*)(&Bs[m * PB + c * 8]) = br[i];
        }
    };

    f32x4 acc[4][4] = {};
    loadB(0);
    writeB(0);
#pragma unroll
    for (int s = 0; s < S; ++s) {
        if (s + 1 < S) loadB(s + 1);
        __syncthreads();
        const unsigned short* Bs = lds + 16384 + (s & 1) * 10240;
        bf16x8 af[4], bfr[4];
#pragma unroll
        for (int mt = 0; mt < 4; ++mt) {
            int row = wm * 64 + mt * 16 + l15;
            af[mt] = *(const bf16x8*)(&As[row * 128 + ((s * 32 + q * 8) ^ ((row & 7) << 3))]);
        }
#pragma unroll
        for (int nt = 0; nt < 4; ++nt)
            bfr[nt] = *(const bf16x8*)(&Bs[(wn * 64 + nt * 16 + l15) * PB + q * 8]);
#pragma unroll
        for (int mt = 0; mt < 4; ++mt)
#pragma unroll
            for (int nt = 0; nt < 4; ++nt)
                acc[mt][nt] = __builtin_amdgcn_mfma_f32_16x16x32_bf16(
                    af[mt], bfr[nt], acc[mt][nt], 0, 0, 0);
        if (s + 1 < S) writeB((s + 1) & 1);
    }
    __syncthreads();  // all frag reads done; alias h1t over A+B

    // ---- Epilogue: BN partials (2 rows/block) + staged h1 tile (padded) ----
#pragma unroll
    for (int nt = 0; nt < 4; ++nt) {
        int col = wn * 64 + nt * 16 + l15;
        float b = b1[col];
        float s = 0.f, ss = 0.f;
#pragma unroll
        for (int mt = 0; mt < 4; ++mt) {
#pragma unroll
            for (int r = 0; r < 4; ++r) {
                int rowL = wm * 64 + mt * 16 + q * 4 + r;
                long row = row0 + rowL;
                float v = acc[mt][nt][r] + b;
                if (row < M) { s += v; ss += v * v; }
                h1t[rowL * PH + col] = f2bf(v);
            }
        }
        s += __shfl_xor(s, 16, 64);  s += __shfl_xor(s, 32, 64);
        ss += __shfl_xor(ss, 16, 64); ss += __shfl_xor(ss, 32, 64);
        if (lane < 16) {
            long pr = (long)blockIdx.x * 2 + wm;
            partials[pr * 512 + col] = s;
            partials[pr * 512 + 256 + col] = ss;
        }
    }
    __syncthreads();
    {   // contiguous stores: thread t -> row t>>2, 64-col segment (t&3)*64
        int srow = tid >> 2, scol = (tid & 3) * 64;
        unsigned short* dst = h1 + (row0 + srow) * DIM_H + scol;
        const unsigned short* srcp = &h1t[srow * PH + scol];
#pragma unroll
        for (int j = 0; j < 8; ++j)
            *(bf16x8*)(dst + j * 8) = *(const bf16x8*)(srcp + j * 8);
    }
}

// ---------------- fused GEMM2 + GEMM3, 128x256 tile, 512 threads ----------------
__global__ __launch_bounds__(512, 4) void gemm23_kernel(
    const unsigned short* __restrict__ h1, const unsigned short* __restrict__ W2t,
    const float* __restrict__ b2,
    const float* __restrict__ scale, const float* __restrict__ shift,
    const unsigned short* __restrict__ Wlt, const float* __restrict__ blin,
    float* __restrict__ out, int M) {
    constexpr int S = 8;
    constexpr int PA = 40, PB = 40, PH = 264;
    constexpr int STAGE = 128 * PA + 256 * PB;
    __shared__ __align__(16) unsigned short lds[128 * PH];
    unsigned short* h2t = lds;

    int tid = threadIdx.x;
    int wave = tid >> 6, lane = tid & 63;
    int wm = wave >> 2, wn = wave & 3;
    int l15 = lane & 15, q = lane >> 4;
    long row0 = (long)blockIdx.x * 128;

    int am = tid >> 2, ac = tid & 3;
    bf16x8 ar, br[2];
    auto loadAB = [&](int s) {
        ar = *(const bf16x8*)(h1 + (row0 + am) * DIM_H + s * 32 + ac * 8);
#pragma unroll
        for (int i = 0; i < 2; ++i) {
            int ch = tid + i * 512;
            int m = ch >> 2, c = ch & 3;
            br[i] = *(const bf16x8*)(W2t + m * DIM_H + s * 32 + c * 8);
        }
    };
    auto writeAB = [&](int s, int buf) {
        unsigned short* As = lds + buf * STAGE;
        unsigned short* Bs = As + 128 * PA;
        {
            int kb = s * 32 + ac * 8;
            float4 sc0 = *(const float4*)(scale + kb);
            float4 sc1 = *(const float4*)(scale + kb + 4);
            float4 sh0 = *(const float4*)(shift + kb);
            float4 sh1 = *(const float4*)(shift + kb + 4);
            float scv[8] = {sc0.x, sc0.y, sc0.z, sc0.w, sc1.x, sc1.y, sc1.z, sc1.w};
            float shv[8] = {sh0.x, sh0.y, sh0.z, sh0.w, sh1.x, sh1.y, sh1.z, sh1.w};
            bf16x8 v = ar;
#pragma unroll
            for (int j = 0; j < 8; ++j) {
                float f = bf2f((unsigned short)v[j]);
                f = fmaxf(f * scv[j] + shv[j], 0.f);
                v[j] = (short)f2bf(f);
            }
            *(bf16x8*)(&As[am * PA + ac * 8]) = v;
        }
#pragma unroll
        for (int i = 0; i < 2; ++i) {
            int ch = tid + i * 512;
            int m = ch >> 2, c = ch & 3;
            *(bf16x8*)(&Bs[m * PB + c * 8]) = br[i];
        }
    };

    f32x4 acc[4][4] = {};
    loadAB(0);
    writeAB(0, 0);
#pragma unroll
    for (int s = 0; s < S; ++s) {
        if (s + 1 < S) loadAB(s + 1);
        __syncthreads();
        const unsigned short* As = lds + (s & 1) * STAGE;
        const unsigned short* Bs = As + 128 * PA;
        bf16x8 af[4], bfr[4];
#pragma unroll
        for (int mt = 0; mt < 4; ++mt)
            af[mt] = *(const bf16x8*)(&As[(wm * 64 + mt * 16 + l15) * PA + q * 8]);
#pragma unroll
        for (int nt = 0; nt < 4; ++nt)
            bfr[nt] = *(const bf16x8*)(&Bs[(wn * 64 + nt * 16 + l15) * PB + q * 8]);
#pragma unroll
        for (int mt = 0; mt < 4; ++mt)
#pragma unroll
            for (int nt = 0; nt < 4; ++nt)
                acc[mt][nt] = __builtin_amdgcn_mfma_f32_16x16x32_bf16(
                    af[mt], bfr[nt], acc[mt][nt], 0, 0, 0);
        if (s + 1 < S) writeAB(s + 1, (s + 1) & 1);
    }
    __syncthreads();

#pragma unroll
    for (int nt = 0; nt < 4; ++nt) {
        int colL = wn * 64 + nt * 16 + l15;
        float b = b2[colL];
#pragma unroll
        for (int mt = 0; mt < 4; ++mt)
#pragma unroll
            for (int r = 0; r < 4; ++r) {
                int rowL = wm * 64 + mt * 16 + q * 4 + r;
                h2t[rowL * PH + colL] = f2bf(fmaxf(acc[mt][nt][r] + b, 0.f));
            }
    }
    __syncthreads();

    f32x4 acc3[3] = {};
#pragma unroll
    for (int s = 0; s < 8; ++s) {
        bf16x8 a3 = *(const bf16x8*)(&h2t[(wave * 16 + l15) * PH + s * 32 + q * 8]);
#pragma unroll
        for (int nt = 0; nt < 3; ++nt) {
            bf16x8 b3 = *(const bf16x8*)(Wlt + (nt * 16 + l15) * 256 + s * 32 + q * 8);
            acc3[nt] = __builtin_amdgcn_mfma_f32_16x16x32_bf16(a3, b3, acc3[nt], 0, 0, 0);
        }
    }
#pragma unroll
    for (int nt = 0; nt < 3; ++nt) {
        int col = nt * 16 + l15;
        if (col < N_CLASSES) {
            float b = blin[col];
#pragma unroll
            for (int r = 0; r < 4; ++r) {
                long row = row0 + wave * 16 + q * 4 + r;
                if (row < M) out[row * N_CLASSES + col] = acc3[nt][r] + b;
            }
        }
    }
}

extern "C" void kernel_launch(void* const* d_in, const int* in_sizes, int n_in,
                              void* d_out, int out_size, void* d_ws, size_t ws_size,
                              hipStream_t stream) {
    const float* x     = (const float*)d_in[0];
    const int*   ei    = (const int*)d_in[1];
    const float* W1    = (const float*)d_in[2];
    const float* b1    = (const float*)d_in[3];
    const float* gamma = (const float*)d_in[4];
    const float* beta  = (const float*)d_in[5];
    const float* W2    = (const float*)d_in[6];
    const float* b2    = (const float*)d_in[7];
    const float* Wlin  = (const float*)d_in[8];
    const float* blin  = (const float*)d_in[9];
    float* out = (float*)d_out;

    int M  = in_sizes[0] / F_IN;  // 50000
    int nE = in_sizes[1] / 2;     // 600000
    const int* srcIdx = ei;
    const int* dstIdx = ei + nE;
    int nB = (M + 255) / 256;     // 196
    int g128 = (M + 127) / 128;   // 391 (GEMM tiles)
    int XQ = M * 32;
    int ZQ = M / 4;               // hist only (cursor seeded by scan_kernel)

    unsigned short* h1bf  = (unsigned short*)d_ws;                     // M_PAD*256
    unsigned short* xb    = h1bf + (size_t)M_PAD * DIM_H;              // M_PAD*128
    unsigned short* W1t   = xb + (size_t)M_PAD * F_IN;                 // 256*128
    unsigned short* W2t   = W1t + DIM_H * F_IN;                        // 256*256
    unsigned short* Wlt   = W2t + DIM_H * DIM_H;                       // 64*256
    float*          partials = (float*)(Wlt + 64 * DIM_H);             // 2*g128*512
    float*          scale = partials + (size_t)800 * 512;              // 256
    float*          shift = scale + DIM_H;                             // 256
    int*            hist  = (int*)(shift + DIM_H);                     // M
    int*            cursor= hist + M;                                  // M
    int*            start = cursor + M;                                // M+1
    int*            order = start + (M + 1);                           // nE

    int tB = 256;
    prep_kernel<<<(XQ + 114688 + ZQ + 255) / 256, 256, 0, stream>>>(
        x, xb, W1, W2, Wlin, W1t, W2t, Wlt, hist, XQ, ZQ);
    hist_kernel<<<(nE + tB - 1) / tB, tB, 0, stream>>>(dstIdx, hist, nE);
    scan_kernel<<<nB, 256, 0, stream>>>(hist, start, cursor, M, nE);
    fill_kernel<<<(nE + tB - 1) / tB, tB, 0, stream>>>(srcIdx, dstIdx, cursor, order, nE);

    // fused gather + GEMM1 + BN partials (A1 round-trip eliminated)
    gg1_kernel<<<g128, 512, 0, stream>>>(xb, order, start, W1t, b1, h1bf, partials, M);
    bn_reduce_kernel<<<DIM_H, 256, 0, stream>>>(partials, 2 * g128, gamma, beta, scale, shift, M);
    // fused GEMM2 + GEMM3
    gemm23_kernel<<<g128, 512, 0, stream>>>(h1bf, W2t, b2, scale, shift, Wlt, blin, out, M);
}